// Round 11
// baseline (30561.044 us; speedup 1.0000x reference)
//
#include <hip/hip_runtime.h>
#include <hip/hip_fp16.h>
#include <math.h>

#define H      1024
#define LBLP1  33        // LABEL_SIZE + 1
#define NE     4096
#define NS     4096
#define NSTEP  (NE - 1)  // 4095 scan steps
#define TGT    1
#define NWG    256       // launched WGs (election picks 32 on one XCD)
#define SLOTS  32        // scan workgroups (one XCD)
#define THREADS 512      // 8 waves; wave owns 4 units
#define UPWAVE 4
#define RPWAVE 28        // 7 gates * 4 units
#define NLDS   9         // rows per wave in LDS (72 rows = 144 KB)
#define NREG   19        // rows per wave in registers (152 VGPR)
#define SENT   0xFFFFFFFFu

__device__ __forceinline__ float wave_sum(float v) {
#pragma unroll
    for (int o = 32; o > 0; o >>= 1) v += __shfl_xor(v, o, 64);
    return v;
}
__device__ __forceinline__ float softplusf(float x) {
    return x > 0.f ? x + log1pf(expf(-x)) : log1pf(expf(x));
}
__device__ __forceinline__ float sigmoidf(float x) {
    return 1.f / (1.f + expf(-x));
}

#if __has_builtin(__builtin_amdgcn_cvt_pkrtz) && __has_builtin(__builtin_amdgcn_fdot2)
using half2_t = decltype(__builtin_amdgcn_cvt_pkrtz(0.f, 0.f));
__device__ __forceinline__ float dot2(unsigned u, unsigned h, float c) {
    return __builtin_amdgcn_fdot2(__builtin_bit_cast(half2_t, u),
                                  __builtin_bit_cast(half2_t, h), c, false);
}
#else
__device__ __forceinline__ float dot2(unsigned u, unsigned h, float c) {
    float2 fa = __half22float2(__builtin_bit_cast(__half2, u));
    float2 fb = __half22float2(__builtin_bit_cast(__half2, h));
    c = fmaf(fa.x, fb.x, c);
    c = fmaf(fa.y, fb.y, c);
    return c;
}
#endif

__device__ __forceinline__ unsigned pkhalf2(float a, float b) {
    return __builtin_bit_cast(unsigned, __floats2half2_rn(a, b));
}

// EmbT[l*H + k] = Emb[k*LBLP1 + l]
__global__ void embT_kernel(const float* __restrict__ Emb, float* __restrict__ EmbT) {
    int l = blockIdx.x;
    for (int k = threadIdx.x; k < H; k += blockDim.x)
        EmbT[(size_t)l * H + k] = Emb[(size_t)k * LBLP1 + l];
}

// WEmb[row*33 + l] = dot(W[row,:], EmbT[l,:]) + d[row]
__global__ void wemb_kernel(const float* __restrict__ W, const float* __restrict__ EmbT,
                            const float* __restrict__ dbias, float* __restrict__ WEmb) {
    int row  = blockIdx.x;
    int wave = threadIdx.x >> 6;
    int lane = threadIdx.x & 63;
    __shared__ float wrow[H];
    for (int i = threadIdx.x; i < H; i += blockDim.x) wrow[i] = W[(size_t)row * H + i];
    __syncthreads();
    float db = dbias[row];
    for (int l = wave; l < LBLP1; l += 4) {
        const float* ec = EmbT + (size_t)l * H;
        float a = 0.f;
#pragma unroll
        for (int m = 0; m < 16; ++m) {
            int k = lane + (m << 6);
            a = fmaf(wrow[k], ec[k], a);
        }
        a = wave_sum(a);
        if (lane == 0) WEmb[(size_t)row * LBLP1 + l] = a + db;
    }
}

// pack U rows fp32 -> f16x2 dwords: Upk[row][p] holds elems (2p, 2p+1)
__global__ void upk_kernel(const float* __restrict__ U, unsigned* __restrict__ Upk) {
    int row = blockIdx.x;  // 0..7*H-1
    const float4* src = (const float4*)(U + (size_t)row * H);
    uint2* dst = (uint2*)(Upk + (size_t)row * (H / 2));
    for (int j = threadIdx.x; j < H / 4; j += blockDim.x) {
        float4 f = src[j];
        dst[j] = make_uint2(pkhalf2(f.x, f.y), pkhalf2(f.z, f.w));
    }
}

// Single-XCD persistent scan. 32 elected WGs on one XCD; slot owns units
// [32s,32s+32). h exchange: producers PLAIN-store packed f16 pairs (write-
// through into the shared XCD L2) + mirror via agent atomic into L3; consumers
// poll with sc0 loads (L1-bypass, served by the same L2); every 4th spin reads
// the L3 mirror for guaranteed liveness.
__global__
__attribute__((amdgpu_flat_work_group_size(THREADS, THREADS), amdgpu_waves_per_eu(2, 2)))
void scan_kernel(const unsigned* __restrict__ Upk, const float* __restrict__ WEmb,
                 const int* __restrict__ label_seq, const float* __restrict__ time_seq,
                 int* __restrict__ ctl, unsigned* __restrict__ hL2,
                 unsigned* __restrict__ hL3,
                 float* __restrict__ all_h, float* __restrict__ all_o,
                 float* __restrict__ all_cb, float* __restrict__ all_cc,
                 float* __restrict__ all_dl) {
    const int tid  = threadIdx.x;
    const int wave = tid >> 6;
    const int lane = tid & 63;

    // ---------------- election (proven in R7/R8) ----------------
    __shared__ int s_slot;
    if (tid == 0) {
        unsigned xcc;
        asm volatile("s_getreg_b32 %0, hwreg(HW_REG_XCC_ID)" : "=s"(xcc));
        int myslot = atomicAdd(&ctl[xcc & 7], 1);
        if (myslot == SLOTS - 1) atomicCAS(&ctl[8], -1, (int)(xcc & 7));
        int win;
        while ((win = __hip_atomic_load(&ctl[8], __ATOMIC_RELAXED,
                                        __HIP_MEMORY_SCOPE_AGENT)) < 0)
            __builtin_amdgcn_s_sleep(8);
        s_slot = ((int)(xcc & 7) == win && myslot < SLOTS) ? myslot : -1;
    }
    __syncthreads();
    const int slot = s_slot;
    if (slot < 0) return;

    // ---------------- LDS layout (dwords) ----------------
    extern __shared__ unsigned smem_u[];
    unsigned* uld    = smem_u;                    // 72 rows * 512 = 36864 (144 KB)
    unsigned* h_pk   = uld + 72 * 512;            // 512
    float*    wscr   = (float*)(h_pk + 512);      // 8 waves * 28 rows * 4 = 896
    float*    h_slot = wscr + 8 * RPWAVE * 4;     // 32

    // ---------------- one-time staging ----------------
#pragma unroll
    for (int i = 0; i < NLDS; ++i) {
        int e = i % 7, j = i / 7;
        int uu = slot * 32 + wave * UPWAVE + j;
        const unsigned* src = Upk + ((size_t)e * H + uu) * 512;
#pragma unroll
        for (int m = 0; m < 8; ++m)
            uld[(wave * NLDS + i) * 512 + lane + (m << 6)] = src[lane + (m << 6)];
    }
    unsigned ureg[NREG][8];
#pragma unroll
    for (int i = 0; i < NREG; ++i) {
        int rr = NLDS + i;
        int e = rr % 7, j = rr / 7;
        int uu = slot * 32 + wave * UPWAVE + j;
        const unsigned* src = Upk + ((size_t)e * H + uu) * 512;
#pragma unroll
        for (int m = 0; m < 8; ++m) ureg[i][m] = src[lane + (m << 6)];
    }
    // per-thread bias pointer (lane rr < 28 handles row rr of this wave)
    const float* bptr = WEmb;
    if (lane < RPWAVE) {
        int e = lane % 7, j = lane / 7;
        int uu = slot * 32 + wave * UPWAVE + j;
        bptr = WEmb + ((size_t)e * H + uu) * LBLP1;
    }
    __syncthreads();

    float c_t = 0.f, cbar = 0.f;   // lanes 0..3 of each wave (unit state)

    for (int t = 0; t < NSTEP; ++t) {
        const int   lab = label_seq[t];
        const float dt  = time_seq[t + 1] - time_seq[t];
        const float bias = (lane < RPWAVE) ? bptr[lab] : 0.f;  // L2, under poll

        // ---- wave 0: acquire h_t; sc0 spins + every-4th agent mirror ----
        if (wave == 0) {
            unsigned v0, v1, v2, v3, v4, v5, v6, v7;
            if (t > 0) {
                const unsigned* srcA = hL2 + (size_t)(t - 1) * 512 + lane;
                const unsigned* srcB = hL3 + (size_t)(t - 1) * 512 + lane;
                int spin = 0;
                for (;;) {
                    if ((spin & 3) == 3) {
                        v0 = __hip_atomic_load(srcB + 0,   __ATOMIC_RELAXED, __HIP_MEMORY_SCOPE_AGENT);
                        v1 = __hip_atomic_load(srcB + 64,  __ATOMIC_RELAXED, __HIP_MEMORY_SCOPE_AGENT);
                        v2 = __hip_atomic_load(srcB + 128, __ATOMIC_RELAXED, __HIP_MEMORY_SCOPE_AGENT);
                        v3 = __hip_atomic_load(srcB + 192, __ATOMIC_RELAXED, __HIP_MEMORY_SCOPE_AGENT);
                        v4 = __hip_atomic_load(srcB + 256, __ATOMIC_RELAXED, __HIP_MEMORY_SCOPE_AGENT);
                        v5 = __hip_atomic_load(srcB + 320, __ATOMIC_RELAXED, __HIP_MEMORY_SCOPE_AGENT);
                        v6 = __hip_atomic_load(srcB + 384, __ATOMIC_RELAXED, __HIP_MEMORY_SCOPE_AGENT);
                        v7 = __hip_atomic_load(srcB + 448, __ATOMIC_RELAXED, __HIP_MEMORY_SCOPE_AGENT);
                    } else {
                        asm volatile(
                            "global_load_dword %0, %8, off sc0\n\t"
                            "global_load_dword %1, %8, off offset:256 sc0\n\t"
                            "global_load_dword %2, %8, off offset:512 sc0\n\t"
                            "global_load_dword %3, %8, off offset:768 sc0\n\t"
                            "global_load_dword %4, %8, off offset:1024 sc0\n\t"
                            "global_load_dword %5, %8, off offset:1280 sc0\n\t"
                            "global_load_dword %6, %8, off offset:1536 sc0\n\t"
                            "global_load_dword %7, %8, off offset:1792 sc0\n\t"
                            "s_waitcnt vmcnt(0)"
                            : "=&v"(v0), "=&v"(v1), "=&v"(v2), "=&v"(v3),
                              "=&v"(v4), "=&v"(v5), "=&v"(v6), "=&v"(v7)
                            : "v"(srcA)
                            : "memory");
                    }
                    bool ok = (v0 != SENT) & (v1 != SENT) & (v2 != SENT) & (v3 != SENT)
                            & (v4 != SENT) & (v5 != SENT) & (v6 != SENT) & (v7 != SENT);
                    if (ok) break;
                    ++spin;
                }
            } else {
                v0 = v1 = v2 = v3 = v4 = v5 = v6 = v7 = 0u;
            }
            h_pk[lane +   0] = v0;  h_pk[lane +  64] = v1;
            h_pk[lane + 128] = v2;  h_pk[lane + 192] = v3;
            h_pk[lane + 256] = v4;  h_pk[lane + 320] = v5;
            h_pk[lane + 384] = v6;  h_pk[lane + 448] = v7;
        }
        __syncthreads();   // bar_A: h_pk ready

        unsigned hreg[8];
#pragma unroll
        for (int m = 0; m < 8; ++m) hreg[m] = h_pk[lane + (m << 6)];

        // ---- 28 rows/wave: dot + 4-level butterfly + 16-lane-group partials ----
#pragma unroll
        for (int rr = 0; rr < RPWAVE; ++rr) {
            float a = 0.f;
            if (rr < NLDS) {
#pragma unroll
                for (int m = 0; m < 8; ++m)
                    a = dot2(uld[(wave * NLDS + rr) * 512 + lane + (m << 6)], hreg[m], a);
            } else {
#pragma unroll
                for (int m = 0; m < 8; ++m)
                    a = dot2(ureg[rr - NLDS][m], hreg[m], a);
            }
            a += __shfl_xor(a, 1, 64);
            a += __shfl_xor(a, 2, 64);
            a += __shfl_xor(a, 4, 64);
            a += __shfl_xor(a, 8, 64);
            if ((lane & 15) == 0)
                wscr[(wave * RPWAVE + rr) * 4 + (lane >> 4)] = a;
        }
        asm volatile("s_waitcnt lgkmcnt(0)" ::: "memory");

        // ---- lanes 0..27: final sum + bias + activation ----
        float act = 0.f;
        if (lane < RPWAVE) {
            const float* wr = wscr + (wave * RPWAVE + lane) * 4;
            float s = wr[0] + wr[1] + wr[2] + wr[3] + bias;
            int e = lane % 7;
            act = (e == 2) ? tanhf(s) : (e == 6) ? softplusf(s) : sigmoidf(s);
        }
        // gather the 7 gates of unit j (all lanes execute the shuffles)
        int b = (lane < UPWAVE ? lane : 0) * 7;
        float ig = __shfl(act, b + 0), fg = __shfl(act, b + 1);
        float zz = __shfl(act, b + 2), oo = __shfl(act, b + 3);
        float ib = __shfl(act, b + 4), fb = __shfl(act, b + 5);
        float dl = __shfl(act, b + 6);

        float c = 0.f, cbn = 0.f, hn = 0.f;
        if (lane < UPWAVE) {
            c   = fmaf(fg, c_t, ig * zz);
            cbn = fmaf(fb, cbar, ib * zz);
            float ctn = cbn + (c - cbn) * expf(-dl * dt);
            hn  = oo * tanhf(ctn);
            c_t = ctn; cbar = cbn;
            h_slot[wave * UPWAVE + lane] = hn;
        }
        __syncthreads();   // bar_B: h_slot ready

        // ---- wave 0, lanes 0..15: pack unit pairs; publish L2 + L3 mirror ----
        if (wave == 0 && lane < 16) {
            unsigned pk = pkhalf2(h_slot[2 * lane], h_slot[2 * lane + 1]);
            unsigned* dA = hL2 + (size_t)t * 512 + slot * 16 + lane;
            asm volatile("global_store_dword %0, %1, off"
                         :: "v"(dA), "v"(pk) : "memory");          // plain -> XCD L2
            __hip_atomic_store(hL3 + (size_t)t * 512 + slot * 16 + lane, pk,
                               __ATOMIC_RELAXED, __HIP_MEMORY_SCOPE_AGENT);  // mirror -> L3
        }

        // ---- bookkeeping (fire-and-forget) ----
        if (lane < UPWAVE) {
            size_t pos = (size_t)t * H + slot * 32 + wave * UPWAVE + lane;
            all_h [pos] = hn;
            all_o [pos] = oo;
            all_cb[pos] = cbn;
            all_cc[pos] = c;
            all_dl[pos] = dl;
        }
    }
}

__global__ void term1_kernel(const float* __restrict__ all_h, const int* __restrict__ label_seq,
                             const float* __restrict__ w, const float* __restrict__ log_s,
                             const int* __restrict__ ignore_first, float* __restrict__ acc) {
    int beg = (*ignore_first) ? 1 : 0;
    int j = blockIdx.x;
    if (j >= (NSTEP - 1 - beg)) return;
    if (label_seq[1 + beg + j] != TGT) return;
    const float* hrow = all_h + (size_t)(beg + j) * H;
    const float* w0 = w + (TGT - 1) * H;
    float part = 0.f;
    for (int i = threadIdx.x; i < H; i += blockDim.x) part += hrow[i] * w0[i];
    __shared__ float red[4];
    part = wave_sum(part);
    if ((threadIdx.x & 63) == 0) red[threadIdx.x >> 6] = part;
    __syncthreads();
    if (threadIdx.x == 0) {
        float tot = red[0] + red[1] + red[2] + red[3];
        float s0 = expf(log_s[TGT - 1]);
        float lam = s0 * softplusf(tot / s0) + 1e-9f;
        atomicAdd(acc, logf(lam));
    }
}

__global__ void term2_kernel(const float* __restrict__ all_o, const float* __restrict__ all_cb,
                             const float* __restrict__ all_cc, const float* __restrict__ all_dl,
                             const int* __restrict__ sim_idx, const float* __restrict__ sim_time,
                             const float* __restrict__ time_seq, const float* __restrict__ w,
                             const float* __restrict__ log_s, float* __restrict__ acc) {
    int i = blockIdx.x;
    int idx = sim_idx[i];
    float dtp = sim_time[i] - time_seq[idx];
    size_t base = (size_t)idx * H;
    const float* w0 = w + (TGT - 1) * H;
    float part = 0.f;
    for (int hh = threadIdx.x; hh < H; hh += blockDim.x) {
        float cb = all_cb[base + hh];
        float cc = all_cc[base + hh];
        float dl = all_dl[base + hh];
        float oo = all_o [base + hh];
        float cs = cb + (cc - cb) * expf(-dl * dtp);
        part += oo * tanhf(cs) * w0[hh];
    }
    __shared__ float red[4];
    part = wave_sum(part);
    if ((threadIdx.x & 63) == 0) red[threadIdx.x >> 6] = part;
    __syncthreads();
    if (threadIdx.x == 0) {
        float tot = red[0] + red[1] + red[2] + red[3];
        float s0 = expf(log_s[TGT - 1]);
        float lam = s0 * softplusf(tot / s0) + 1e-9f;
        atomicAdd(acc + 1, lam);
    }
}

__global__ void finish_kernel(const float* __restrict__ acc, const float* __restrict__ time_seq,
                              float* __restrict__ out) {
    float T = time_seq[NE - 1] - time_seq[0];
    out[0] = -(acc[0] - acc[1] * (T / (float)NS));
}

extern "C" void kernel_launch(void* const* d_in, const int* in_sizes, int n_in,
                              void* d_out, int out_size, void* d_ws, size_t ws_size,
                              hipStream_t stream) {
    const int*   label_seq    = (const int*)  d_in[0];
    const float* time_seq     = (const float*)d_in[1];
    const float* sim_time     = (const float*)d_in[2];
    const int*   sim_idx      = (const int*)  d_in[3];
    const int*   ignore_first = (const int*)  d_in[4];
    const float* Emb   = (const float*)d_in[5];
    const float* W     = (const float*)d_in[6];
    const float* U     = (const float*)d_in[7];
    const float* dbias = (const float*)d_in[8];
    const float* w     = (const float*)d_in[9];
    const float* log_s = (const float*)d_in[10];
    float* out = (float*)d_out;

    float* ws = (float*)d_ws;
    size_t off = 0;
    int*      ctl  = (int*)(ws + off);      off += 16;   // [0..7] roster, [8] winner
    float*    acc  = ws + off;              off += 32;
    float*    EmbT = ws + off;              off += (size_t)LBLP1 * H;
    float*    WEmb = ws + off;              off += (size_t)7 * H * LBLP1;
    off = (off + 3) & ~(size_t)3;
    unsigned* Upk  = (unsigned*)(ws + off); off += (size_t)7 * H * (H / 2);
    unsigned* hL2  = (unsigned*)(ws + off); off += (size_t)NSTEP * 512;
    unsigned* hL3  = (unsigned*)(ws + off); off += (size_t)NSTEP * 512;
    float* all_h  = ws + off;  off += (size_t)NSTEP * H;
    float* all_o  = ws + off;  off += (size_t)NSTEP * H;
    float* all_cb = ws + off;  off += (size_t)NSTEP * H;
    float* all_cc = ws + off;  off += (size_t)NSTEP * H;
    float* all_dl = ws + off;  off += (size_t)NSTEP * H;

    hipMemsetAsync(ctl, 0, 8 * sizeof(int), stream);
    hipMemsetAsync(ctl + 8, 0xFF, sizeof(int), stream);      // winner = -1
    hipMemsetAsync(acc, 0, 2 * sizeof(float), stream);
    hipMemsetAsync(hL2, 0xFF, (size_t)NSTEP * 512 * 4, stream);
    hipMemsetAsync(hL3, 0xFF, (size_t)NSTEP * 512 * 4, stream);

    hipLaunchKernelGGL(embT_kernel, dim3(LBLP1), dim3(256), 0, stream, Emb, EmbT);
    hipLaunchKernelGGL(wemb_kernel, dim3(7 * H), dim3(256), 0, stream,
                       W, EmbT, dbias, WEmb);
    hipLaunchKernelGGL(upk_kernel, dim3(7 * H), dim3(256), 0, stream, U, Upk);

    // LDS: 72 U rows (147456 B) + h_pk (2048 B) + wscr (3584 B) + h_slot (128 B)
    unsigned int smem_bytes = (unsigned int)((72 * 512 + 512) * 4
                                             + (8 * RPWAVE * 4 + 32) * 4);
    hipFuncSetAttribute((const void*)scan_kernel, hipFuncAttributeMaxDynamicSharedMemorySize,
                        (int)smem_bytes);
    void* args[] = { (void*)&Upk, (void*)&WEmb, (void*)&label_seq, (void*)&time_seq,
                     (void*)&ctl, (void*)&hL2, (void*)&hL3, (void*)&all_h, (void*)&all_o,
                     (void*)&all_cb, (void*)&all_cc, (void*)&all_dl };
    hipLaunchCooperativeKernel((void*)scan_kernel, dim3(NWG), dim3(THREADS),
                               args, smem_bytes, stream);

    hipLaunchKernelGGL(term1_kernel, dim3(NSTEP - 1), dim3(256), 0, stream,
                       all_h, label_seq, w, log_s, ignore_first, acc);
    hipLaunchKernelGGL(term2_kernel, dim3(NS), dim3(256), 0, stream,
                       all_o, all_cb, all_cc, all_dl, sim_idx, sim_time, time_seq, w, log_s, acc);
    hipLaunchKernelGGL(finish_kernel, dim3(1), dim3(1), 0, stream, acc, time_seq, out);
}

// Round 12
// 16079.362 us; speedup vs baseline: 1.9006x; 1.9006x over previous
//
#include <hip/hip_runtime.h>
#include <math.h>

#define H      1024
#define LBLP1  33        // LABEL_SIZE + 1
#define NE     4096
#define NS     4096
#define NSTEP  (NE - 1)  // 4095 scan steps
#define TGT    1
#define NWG    256
#define UPW    4         // hidden units per workgroup
#define ROWS   28        // 7 gates * 4 units
#define THREADS 1024
#define NCPY   4         // replicated h copies (64 consumer WGs each)
#define SENT   0xFFFFFFFFu

__device__ __forceinline__ float wave_sum(float v) {
#pragma unroll
    for (int o = 32; o > 0; o >>= 1) v += __shfl_xor(v, o, 64);
    return v;
}

__device__ __forceinline__ float softplusf(float x) {
    return x > 0.f ? x + log1pf(expf(-x)) : log1pf(expf(x));
}
__device__ __forceinline__ float sigmoidf(float x) {
    return 1.f / (1.f + expf(-x));
}

// round-to-nearest-even fp32 -> bf16 (finite inputs; |h|<1 so never 0xFFFF)
__device__ __forceinline__ unsigned short f2bf(float f) {
    unsigned u = __float_as_uint(f);
    return (unsigned short)((u + 0x7FFFu + ((u >> 16) & 1u)) >> 16);
}

// EmbT[l*H + k] = Emb[k*LBLP1 + l]
__global__ void embT_kernel(const float* __restrict__ Emb, float* __restrict__ EmbT) {
    int l = blockIdx.x;
    for (int k = threadIdx.x; k < H; k += blockDim.x)
        EmbT[(size_t)l * H + k] = Emb[(size_t)k * LBLP1 + l];
}

// WEmb[row*33 + l] = dot(W[row,:], EmbT[l,:]) + d[row];  row = e*H + h
__global__ void wemb_kernel(const float* __restrict__ W, const float* __restrict__ EmbT,
                            const float* __restrict__ dbias, float* __restrict__ WEmb) {
    int row  = blockIdx.x;
    int wave = threadIdx.x >> 6;
    int lane = threadIdx.x & 63;
    __shared__ float wrow[H];
    for (int i = threadIdx.x; i < H; i += blockDim.x) wrow[i] = W[(size_t)row * H + i];
    __syncthreads();
    float db = dbias[row];
    for (int l = wave; l < LBLP1; l += 4) {
        const float* ec = EmbT + (size_t)l * H;
        float a = 0.f;
#pragma unroll
        for (int m = 0; m < 16; ++m) {
            int k = lane + (m << 6);
            a = fmaf(wrow[k], ec[k], a);
        }
        a = wave_sum(a);
        if (lane == 0) WEmb[(size_t)row * LBLP1 + l] = a + db;
    }
}

// Persistent dataflow scan, fan-out edition (R5 champion + publish-early).
// 256 WGs x 1024 threads. Producers publish their 4-unit h slice as ONE packed
// 8B bf16 atomic store into NCPY replicated buffers; each group of 64 WGs polls
// only its own copy (64 readers/line); bf16 payload = 2 KB poll footprint.
__global__ __launch_bounds__(THREADS)
void scan_kernel(const float* __restrict__ WEmb, const float* __restrict__ U,
                 const int* __restrict__ label_seq, const float* __restrict__ time_seq,
                 unsigned short* __restrict__ hcp,
                 float* __restrict__ all_h, float* __restrict__ all_o,
                 float* __restrict__ all_cb, float* __restrict__ all_cc,
                 float* __restrict__ all_dl) {
    const int tid  = threadIdx.x;
    const int wg   = blockIdx.x;
    const int wave = tid >> 6;
    const int lane = tid & 63;
    const int mycopy = wg >> 6;   // 64 WGs per copy

    extern __shared__ float smem[];
    float* Uld    = smem;                 // ROWS * H   (16B-aligned)
    float* h_sh   = Uld + ROWS * H;       // H          (16B-aligned)
    float* act_sh = h_sh + H;             // 32
    float* wes    = act_sh + 32;          // ROWS * LBLP1

    // One-time staging: 28 rows of U (coalesced over k) + WEmb slice.
    for (int idx = tid; idx < ROWS * H; idx += THREADS) {
        int r = idx >> 10, k = idx & (H - 1);
        int e = r >> 2, j = r & 3;
        Uld[idx] = U[((size_t)e * H + (wg * UPW + j)) * H + k];
    }
    for (int idx = tid; idx < ROWS * LBLP1; idx += THREADS) {
        int r = idx / LBLP1, l = idx - r * LBLP1;
        int e = r >> 2, j = r & 3;
        wes[idx] = WEmb[((size_t)e * H + (wg * UPW + j)) * LBLP1 + l];
    }
    __syncthreads();

    float c_t = 0.f, cbar = 0.f;
    const float4* h4 = (const float4*)h_sh;

    for (int t = 0; t < NSTEP; ++t) {
        const int   lab = label_seq[t];
        const float dt  = time_seq[t + 1] - time_seq[t];

        // gate biases for this wave's rows (waves 2..15 own rows 2*(w-2), +1)
        float gb0 = 0.f, gb1 = 0.f;
        int r0 = (wave - 2) << 1;
        if (wave >= 2) {
            gb0 = wes[r0 * LBLP1 + lab];
            gb1 = wes[(r0 + 1) * LBLP1 + lab];
        }

        // --- wave 0: acquire h_t from own bf16 copy; redistribute via LDS ---
        if (wave == 0) {
            unsigned v[8];
            if (t > 0) {
                const unsigned* src = (const unsigned*)
                    (hcp + ((size_t)mycopy * NSTEP + (t - 1)) * H);
                for (;;) {
                    bool ok = true;
#pragma unroll
                    for (int j = 0; j < 8; ++j)
                        v[j] = __hip_atomic_load(src + (j << 6) + lane,
                                                 __ATOMIC_RELAXED, __HIP_MEMORY_SCOPE_AGENT);
#pragma unroll
                    for (int j = 0; j < 8; ++j) ok &= (v[j] != SENT);
                    if (ok) break;
                }
            } else {
#pragma unroll
                for (int j = 0; j < 8; ++j) v[j] = 0;
            }
            // unpack 2 bf16 per dword; lane-interleaved float2 stores (2-way, free)
#pragma unroll
            for (int j = 0; j < 8; ++j) {
                float2 f2;
                if (t > 0) {
                    f2.x = __uint_as_float(v[j] << 16);
                    f2.y = __uint_as_float(v[j] & 0xFFFF0000u);
                } else f2 = make_float2(0.f, 0.f);
                ((float2*)h_sh)[(j << 6) + lane] = f2;
            }
        }
        __syncthreads();   // sync_a: h_sh ready

        // --- dots on waves 2..15 (2 rows each), activation fused ---
        if (wave >= 2) {
            float4 hr[4];
#pragma unroll
            for (int m = 0; m < 4; ++m) hr[m] = h4[(m << 6) + lane];
#pragma unroll
            for (int i = 0; i < 2; ++i) {
                int r = r0 + i;
                const float4* u4 = (const float4*)(Uld + (r << 10));
                float a = 0.f;
#pragma unroll
                for (int m = 0; m < 4; ++m) {
                    float4 u = u4[(m << 6) + lane];
                    a = fmaf(u.x, hr[m].x, a); a = fmaf(u.y, hr[m].y, a);
                    a = fmaf(u.z, hr[m].z, a); a = fmaf(u.w, hr[m].w, a);
                }
                a = wave_sum(a);
                float g = (i ? gb1 : gb0) + a;
                int e = r >> 2;
                float act;
                if (e == 2)      act = tanhf(g);
                else if (e == 6) act = softplusf(g);
                else             act = sigmoidf(g);
                if (lane == 0) act_sh[r] = act;
            }
        }
        __syncthreads();   // sync_b: act_sh ready

        // --- state update; publish FIRST, bookkeeping after (wave 0, lanes 0..3) ---
        if (tid < UPW) {
            float i_g = act_sh[tid],      f_g = act_sh[4 + tid];
            float z   = act_sh[8 + tid],  o   = act_sh[12 + tid];
            float i_b = act_sh[16 + tid], f_b = act_sh[20 + tid];
            float dl  = act_sh[24 + tid];
            float c   = fmaf(f_g, c_t, i_g * z);
            float cbn = fmaf(f_b, cbar, i_b * z);
            float ctn = cbn + (c - cbn) * expf(-dl * dt);
            float hn  = o * tanhf(ctn);
            c_t = ctn; cbar = cbn;
            // gather the 4 unit values into lane 0, pack, fan out to NCPY copies
            float h0 = __shfl(hn, 0), h1 = __shfl(hn, 1);
            float h2 = __shfl(hn, 2), h3 = __shfl(hn, 3);
            if (tid == 0) {
                unsigned long long pk =
                    (unsigned long long)f2bf(h0)
                  | ((unsigned long long)f2bf(h1) << 16)
                  | ((unsigned long long)f2bf(h2) << 32)
                  | ((unsigned long long)f2bf(h3) << 48);
                unsigned long long* base = (unsigned long long*)hcp;
#pragma unroll
                for (int cdst = 0; cdst < NCPY; ++cdst) {
                    __hip_atomic_store(base + ((size_t)cdst * NSTEP + t) * (H / 4) + wg,
                                       pk, __ATOMIC_RELAXED, __HIP_MEMORY_SCOPE_AGENT);
                }
            }
            // bookkeeping after the publish (fire-and-forget)
            size_t p = (size_t)t * H + wg * UPW + tid;
            all_h [p] = hn;
            all_o [p] = o;
            all_cb[p] = cbn;
            all_cc[p] = c;
            all_dl[p] = dl;
        }
        // no global barrier: step-(t+1) polls provide cross-WG ordering;
        // h_sh/act_sh rewrite hazards covered by sync_a/sync_b.
    }
}

__global__ void term1_kernel(const float* __restrict__ all_h, const int* __restrict__ label_seq,
                             const float* __restrict__ w, const float* __restrict__ log_s,
                             const int* __restrict__ ignore_first, float* __restrict__ acc) {
    int beg = (*ignore_first) ? 1 : 0;
    int j = blockIdx.x;
    if (j >= (NSTEP - 1 - beg)) return;
    if (label_seq[1 + beg + j] != TGT) return;
    const float* hrow = all_h + (size_t)(beg + j) * H;
    const float* w0 = w + (TGT - 1) * H;
    float part = 0.f;
    for (int i = threadIdx.x; i < H; i += blockDim.x) part += hrow[i] * w0[i];
    __shared__ float red[4];
    part = wave_sum(part);
    if ((threadIdx.x & 63) == 0) red[threadIdx.x >> 6] = part;
    __syncthreads();
    if (threadIdx.x == 0) {
        float tot = red[0] + red[1] + red[2] + red[3];
        float s0 = expf(log_s[TGT - 1]);
        float lam = s0 * softplusf(tot / s0) + 1e-9f;
        atomicAdd(acc, logf(lam));
    }
}

__global__ void term2_kernel(const float* __restrict__ all_o, const float* __restrict__ all_cb,
                             const float* __restrict__ all_cc, const float* __restrict__ all_dl,
                             const int* __restrict__ sim_idx, const float* __restrict__ sim_time,
                             const float* __restrict__ time_seq, const float* __restrict__ w,
                             const float* __restrict__ log_s, float* __restrict__ acc) {
    int i = blockIdx.x;
    int idx = sim_idx[i];
    float dtp = sim_time[i] - time_seq[idx];
    size_t base = (size_t)idx * H;
    const float* w0 = w + (TGT - 1) * H;
    float part = 0.f;
    for (int hh = threadIdx.x; hh < H; hh += blockDim.x) {
        float cb = all_cb[base + hh];
        float cc = all_cc[base + hh];
        float dl = all_dl[base + hh];
        float oo = all_o [base + hh];
        float cs = cb + (cc - cb) * expf(-dl * dtp);
        part += oo * tanhf(cs) * w0[hh];
    }
    __shared__ float red[4];
    part = wave_sum(part);
    if ((threadIdx.x & 63) == 0) red[threadIdx.x >> 6] = part;
    __syncthreads();
    if (threadIdx.x == 0) {
        float tot = red[0] + red[1] + red[2] + red[3];
        float s0 = expf(log_s[TGT - 1]);
        float lam = s0 * softplusf(tot / s0) + 1e-9f;
        atomicAdd(acc + 1, lam);
    }
}

__global__ void finish_kernel(const float* __restrict__ acc, const float* __restrict__ time_seq,
                              float* __restrict__ out) {
    float T = time_seq[NE - 1] - time_seq[0];
    out[0] = -(acc[0] - acc[1] * (T / (float)NS));
}

extern "C" void kernel_launch(void* const* d_in, const int* in_sizes, int n_in,
                              void* d_out, int out_size, void* d_ws, size_t ws_size,
                              hipStream_t stream) {
    const int*   label_seq    = (const int*)  d_in[0];
    const float* time_seq     = (const float*)d_in[1];
    const float* sim_time     = (const float*)d_in[2];
    const int*   sim_idx      = (const int*)  d_in[3];
    const int*   ignore_first = (const int*)  d_in[4];
    const float* Emb   = (const float*)d_in[5];
    const float* W     = (const float*)d_in[6];
    const float* U     = (const float*)d_in[7];
    const float* dbias = (const float*)d_in[8];
    const float* w     = (const float*)d_in[9];
    const float* log_s = (const float*)d_in[10];
    float* out = (float*)d_out;

    float* ws = (float*)d_ws;
    size_t off = 0;
    float* acc    = ws + off;  off += 32;                    // [0]=term1, [1]=term2-sum
    float* EmbT   = ws + off;  off += (size_t)LBLP1 * H;
    float* WEmb   = ws + off;  off += (size_t)7 * H * LBLP1;
    off = (off + 3) & ~(size_t)3;                            // 16B align
    float* all_h  = ws + off;  off += (size_t)NSTEP * H;
    float* all_o  = ws + off;  off += (size_t)NSTEP * H;
    float* all_cb = ws + off;  off += (size_t)NSTEP * H;
    float* all_cc = ws + off;  off += (size_t)NSTEP * H;
    float* all_dl = ws + off;  off += (size_t)NSTEP * H;
    unsigned short* hcp = (unsigned short*)(ws + off);       // NCPY*NSTEP*H bf16
    off += (size_t)NCPY * NSTEP * H / 2;                     // in float units

    hipMemsetAsync(acc, 0, 2 * sizeof(float), stream);
    // sentinel-fill the bf16 fan-out buffers (0xFFFF bf16 = NaN, never produced)
    hipMemsetAsync(hcp, 0xFF, (size_t)NCPY * NSTEP * H * sizeof(unsigned short), stream);

    hipLaunchKernelGGL(embT_kernel, dim3(LBLP1), dim3(256), 0, stream, Emb, EmbT);
    hipLaunchKernelGGL(wemb_kernel, dim3(7 * H), dim3(256), 0, stream,
                       W, EmbT, dbias, WEmb);

    unsigned int smem_bytes = (unsigned int)((ROWS * H + H + 32 + ROWS * LBLP1) * sizeof(float));
    hipFuncSetAttribute((const void*)scan_kernel, hipFuncAttributeMaxDynamicSharedMemorySize,
                        (int)smem_bytes);
    void* args[] = { (void*)&WEmb, (void*)&U, (void*)&label_seq, (void*)&time_seq,
                     (void*)&hcp, (void*)&all_h, (void*)&all_o, (void*)&all_cb,
                     (void*)&all_cc, (void*)&all_dl };
    // cooperative launch only for the co-residency guarantee (no grid.sync inside)
    hipLaunchCooperativeKernel((void*)scan_kernel, dim3(NWG), dim3(THREADS),
                               args, smem_bytes, stream);

    hipLaunchKernelGGL(term1_kernel, dim3(NSTEP - 1), dim3(256), 0, stream,
                       all_h, label_seq, w, log_s, ignore_first, acc);
    hipLaunchKernelGGL(term2_kernel, dim3(NS), dim3(256), 0, stream,
                       all_o, all_cb, all_cc, all_dl, sim_idx, sim_time, time_seq, w, log_s, acc);
    hipLaunchKernelGGL(finish_kernel, dim3(1), dim3(1), 0, stream, acc, time_seq, out);
}